// Round 10
// baseline (271.564 us; speedup 1.0000x reference)
//
#include <hip/hip_runtime.h>
#include <hip/hip_bf16.h>

typedef unsigned short u16;
typedef __bf16 bf16x8 __attribute__((ext_vector_type(8)));
typedef unsigned int u32x4 __attribute__((ext_vector_type(4)));
typedef float f32x4 __attribute__((ext_vector_type(4)));

#define SEQ 2048
#define DMODEL 512
#define NHEAD 8
#define DFF 2048
#define NBATCH 8
#define MROWS (NBATCH * SEQ)

// 0.125 * log2(e): folded into w_q/b_q so attn softmax is exp2(s) directly
#define C1_FOLD 0.18033688f

__device__ __forceinline__ u16 f2b(float f) {
    __hip_bfloat16 h = __float2bfloat16(f);
    u16 u;
    __builtin_memcpy(&u, &h, 2);
    return u;
}

__device__ __forceinline__ unsigned int pack2(float a, float b) {
    float2 f{a, b};
    __hip_bfloat162 h = __float22bfloat162_rn(f);
    unsigned int u;
    __builtin_memcpy(&u, &h, 4);
    return u;
}

__device__ __forceinline__ float ex2(float x) {
#if __has_builtin(__builtin_amdgcn_exp2f)
    return __builtin_amdgcn_exp2f(x);
#else
    return exp2f(x);
#endif
}

// async global->LDS, 16B per lane. LDS dest must be wave-uniform base; lane i
// lands at base + i*16.
__device__ __forceinline__ void gload_lds16(const void* g, void* lds) {
    auto* gp = reinterpret_cast<const __attribute__((address_space(1))) unsigned int*>(
        reinterpret_cast<uintptr_t>(g));
    auto* lp = reinterpret_cast<__attribute__((address_space(3))) unsigned int*>(
        reinterpret_cast<uintptr_t>(lds));
    __builtin_amdgcn_global_load_lds(gp, lp, 16, 0, 0);
}

// ---------------------------------------------------------------------------
// Weight cast fp32 -> bf16 (6 matrices in one launch). w_q scaled by C1.
// ---------------------------------------------------------------------------
__global__ __launch_bounds__(256) void cast_weights(
    const float* __restrict__ w0, const float* __restrict__ w1,
    const float* __restrict__ w2, const float* __restrict__ w3,
    const float* __restrict__ w4, const float* __restrict__ w5,
    u16* __restrict__ d0, u16* __restrict__ d1, u16* __restrict__ d2,
    u16* __restrict__ d3, u16* __restrict__ d4, u16* __restrict__ d5) {
    int blk = blockIdx.x;
    const float* s;
    u16* d;
    int base;
    float sc = 1.0f;
    if (blk < 512) {
        int seg = blk >> 7, lb = blk & 127;
        s = seg == 0 ? w0 : seg == 1 ? w1 : seg == 2 ? w2 : w3;
        d = seg == 0 ? d0 : seg == 1 ? d1 : seg == 2 ? d2 : d3;
        base = lb * 2048;
        if (seg == 0) sc = C1_FOLD;
    } else if (blk < 1024) {
        s = w4; d = d4; base = (blk - 512) * 2048;
    } else {
        s = w5; d = d5; base = (blk - 1024) * 2048;
    }
    int i = base + threadIdx.x * 8;
    float4 a = *reinterpret_cast<const float4*>(s + i);
    float4 b = *reinterpret_cast<const float4*>(s + i + 4);
    ushort4 oa, ob;
    oa.x = f2b(a.x * sc); oa.y = f2b(a.y * sc);
    oa.z = f2b(a.z * sc); oa.w = f2b(a.w * sc);
    ob.x = f2b(b.x * sc); ob.y = f2b(b.y * sc);
    ob.z = f2b(b.z * sc); ob.w = f2b(b.w * sc);
    *reinterpret_cast<ushort4*>(d + i) = oa;
    *reinterpret_cast<ushort4*>(d + i + 4) = ob;
}

// concat b_q*C1 | b_k | b_v -> bqkv[1536]
__global__ __launch_bounds__(256) void concat_bias(const float* __restrict__ bq,
                                                   const float* __restrict__ bk,
                                                   const float* __restrict__ bv,
                                                   float* __restrict__ dst) {
    int i = blockIdx.x * 256 + threadIdx.x;
    float v = i < 512 ? bq[i] * C1_FOLD : (i < 1024 ? bk[i - 512] : bv[i - 1024]);
    dst[i] = v;
}

// ---------------------------------------------------------------------------
// LayerNorm (unbiased var, ddof=1), fp32 in -> bf16 out. 1 wave / 512-row.
// ---------------------------------------------------------------------------
__global__ __launch_bounds__(256) void ln_rows(const float* __restrict__ x,
                                               u16* __restrict__ out) {
    int row = blockIdx.x * 4 + (threadIdx.x >> 6);
    int l = threadIdx.x & 63;
    const float* xr = x + (size_t)row * DMODEL + l * 8;
    float4 a = *reinterpret_cast<const float4*>(xr);
    float4 b = *reinterpret_cast<const float4*>(xr + 4);
    float s = a.x + a.y + a.z + a.w + b.x + b.y + b.z + b.w;
    float q = a.x * a.x + a.y * a.y + a.z * a.z + a.w * a.w +
              b.x * b.x + b.y * b.y + b.z * b.z + b.w * b.w;
#pragma unroll
    for (int d = 32; d >= 1; d >>= 1) {
        s += __shfl_xor(s, d, 64);
        q += __shfl_xor(q, d, 64);
    }
    float mean = s * (1.f / 512.f);
    float var = (q - 512.f * mean * mean) * (1.f / 511.f);
    float rs = rsqrtf(var + 1e-6f);
    ushort4 o0, o1;
    o0.x = f2b((a.x - mean) * rs); o0.y = f2b((a.y - mean) * rs);
    o0.z = f2b((a.z - mean) * rs); o0.w = f2b((a.w - mean) * rs);
    o1.x = f2b((b.x - mean) * rs); o1.y = f2b((b.y - mean) * rs);
    o1.z = f2b((b.z - mean) * rs); o1.w = f2b((b.w - mean) * rs);
    u16* op = out + (size_t)row * DMODEL + l * 8;
    *reinterpret_cast<ushort4*>(op) = o0;
    *reinterpret_cast<ushort4*>(op + 4) = o1;
}

// ---------------------------------------------------------------------------
// GEMM 256x256 8-phase (T3+T4): BK=64 split in K-halves; 8 waves (2M x 4N),
// per-wave 128x64 out; LDS 128KiB = 2dbuf x 2khalf x (A 16K + B 16K).
// Per K-tile 4 phases: {stage 1 half-tile of t+1; counted vmcnt(6) at
// phases 0,2 (never 0 in steady state); ds_read 4-8 b128; barrier;
// lgkmcnt(0)+sched_barrier; setprio+16 MFMA; barrier}.
// Swizzle: source granule (l&3)^((l>>3)&3); reader 4*l15+(lhi^((l15>>1)&3))
// -> 2 lanes/bank-group per 16-lane phase (free, m136).
// OUTMODE: 0 = bf16 row-major (+RELU), 3 = fused QKV (qk [M][1024] / V8).
// ---------------------------------------------------------------------------
template <bool RELU, int OUTMODE>
__global__ __launch_bounds__(512, 2) void gemm256(
    const u16* __restrict__ A, const u16* __restrict__ W,
    const float* __restrict__ bias,
    void* __restrict__ Cout, void* __restrict__ Cout2, int N, int K) {
    __shared__ u16 LS[2][2][2][8192];  // [dbuf][khalf][mat A/B][16 chunks*512]
    const int tid = threadIdx.x;
    const int l = tid & 63, w = tid >> 6;  // 8 waves
    const int l15 = l & 15, lhi = l >> 4;
    const int m0 = blockIdx.y * 256, n0 = blockIdx.x * 256;
    const int wr = (w >> 2) * 128;  // M-half per wave
    const int wc = (w & 3) * 64;    // N quarter per wave

    f32x4 acc[8][4] = {};

    // reader lane offset within a chunk (u16 elems)
    const int goff = (4 * l15 + (lhi ^ ((l15 >> 1) & 3))) * 8;
    // writer: lane l covers local row l>>2, granule l&3; fetch swizzled col
    const int sgran = ((l & 3) ^ ((l >> 3) & 3)) * 8;
    const int srow = l >> 2;

    auto stageH = [&](int q, int kh, int mat, int ktn) {
#pragma unroll
        for (int i = 0; i < 2; ++i) {
            int c = 2 * w + i;
            const u16* src =
                (mat == 0 ? A : W) +
                (size_t)((mat == 0 ? m0 : n0) + c * 16 + srow) * K + ktn +
                kh * 32 + sgran;
            gload_lds16(src, &LS[q][kh][mat][c * 512]);
        }
    };

    bf16x8 bq[4];  // B k-half fragments, held across the 2 phases of a khalf

    auto phase = [&](int p, int kh, int mh, int stcode, int ktn, int vm) {
        if (stcode >= 0) stageH(p ^ 1, stcode >> 1, stcode & 1, ktn);
        if (vm == 6) asm volatile("s_waitcnt vmcnt(6)" ::: "memory");
        else if (vm == 4) asm volatile("s_waitcnt vmcnt(4)" ::: "memory");
        else if (vm == 0) asm volatile("s_waitcnt vmcnt(0)" ::: "memory");
        bf16x8 aq[4];
        if (mh == 0) {
#pragma unroll
            for (int nf = 0; nf < 4; ++nf)
                bq[nf] = *reinterpret_cast<const bf16x8*>(
                    &LS[p][kh][1][((wc >> 4) + nf) * 512 + goff]);
        }
#pragma unroll
        for (int mf = 0; mf < 4; ++mf)
            aq[mf] = *reinterpret_cast<const bf16x8*>(
                &LS[p][kh][0][((wr >> 4) + mh * 4 + mf) * 512 + goff]);
        __builtin_amdgcn_s_barrier();
        asm volatile("s_waitcnt lgkmcnt(0)" ::: "memory");
        __builtin_amdgcn_sched_barrier(0);
        __builtin_amdgcn_s_setprio(1);
#pragma unroll
        for (int mf = 0; mf < 4; ++mf)
#pragma unroll
            for (int nf = 0; nf < 4; ++nf)
                acc[mh * 4 + mf][nf] = __builtin_amdgcn_mfma_f32_16x16x32_bf16(
                    aq[mf], bq[nf], acc[mh * 4 + mf][nf], 0, 0, 0);
        __builtin_amdgcn_s_setprio(0);
        __builtin_amdgcn_s_barrier();
    };

    auto tileF = [&](int p, int kt, bool pf) {
        int ktn = kt + 64;
        phase(p, 0, 0, pf ? 0 : -1, ktn, pf ? 6 : 4);  // stage A-k0(t+1)
        phase(p, 0, 1, pf ? 1 : -1, ktn, -1);          // stage B-k0(t+1)
        phase(p, 1, 0, pf ? 2 : -1, ktn, pf ? 6 : 0);  // stage A-k1(t+1)
        phase(p, 1, 1, pf ? 3 : -1, ktn, -1);          // stage B-k1(t+1)
    };

    // prologue: stage all 4 half-tiles of K-tile 0 into buf 0
    stageH(0, 0, 0, 0);
    stageH(0, 0, 1, 0);
    stageH(0, 1, 0, 0);
    stageH(0, 1, 1, 0);
    asm volatile("s_waitcnt vmcnt(0)" ::: "memory");
    __builtin_amdgcn_s_barrier();

    const int nt = K >> 6;  // even for all our K (512)
    int kt = 0;
    for (int tt = 0; tt < (nt >> 1) - 1; ++tt) {
        tileF(0, kt, true);
        tileF(1, kt + 64, true);
        kt += 128;
    }
    tileF(0, kt, true);
    tileF(1, kt + 64, false);

    // epilogue: C/D map row = 4*lhi + r, col = l15 (verified m89/m91)
    int colg[4];
    float bv[4];
#pragma unroll
    for (int nf = 0; nf < 4; ++nf) {
        colg[nf] = n0 + wc + nf * 16 + l15;
        bv[nf] = bias[colg[nf]];
    }
#pragma unroll
    for (int mf = 0; mf < 8; ++mf) {
        int rowg = m0 + wr + mf * 16 + 4 * lhi;
#pragma unroll
        for (int nf = 0; nf < 4; ++nf) {
            float v[4];
#pragma unroll
            for (int r = 0; r < 4; ++r) {
                float t = acc[mf][nf][r] + bv[nf];
                if constexpr (RELU) t = fmaxf(t, 0.f);
                v[r] = t;
            }
            if constexpr (OUTMODE == 0) {
                u16* o = (u16*)Cout;
#pragma unroll
                for (int r = 0; r < 4; ++r)
                    o[(size_t)(rowg + r) * N + colg[nf]] = f2b(v[r]);
            } else {
                if (n0 < 1024) {
                    u16* o = (u16*)Cout;  // qk buffer [M][1024]
#pragma unroll
                    for (int r = 0; r < 4; ++r)
                        o[(size_t)(rowg + r) * 1024 + colg[nf]] = f2b(v[r]);
                } else {
                    // V8 (B, S/32, 4, 512, 8): keys rowg..rowg+3 share
                    // (kk, hb, s); j=0..3 -> one contiguous 8B store
                    u16* o = (u16*)Cout2;
                    int bb = rowg >> 11, sloc = rowg & 2047;
                    int dg = colg[nf] - 1024;
                    int kk = sloc >> 5, hb = (sloc >> 4) & 1, ss = (sloc >> 2) & 3;
                    ushort4 pk;
                    pk.x = f2b(v[0]); pk.y = f2b(v[1]);
                    pk.z = f2b(v[2]); pk.w = f2b(v[3]);
                    *reinterpret_cast<ushort4*>(
                        &o[(size_t)(bb * 64 + kk) * 16384 + ss * 4096 + dg * 8 +
                           hb * 4]) = pk;
                }
            }
        }
    }
}

// ---------------------------------------------------------------------------
// GEMM 128x128 (proven): used for WO / FFN2 (N=512). 2-phase dbuf.
// OUTMODE: 1 = fp32 row-major + residual.
// ---------------------------------------------------------------------------
template <bool RELU, bool RESID, int OUTMODE>
__global__ __launch_bounds__(256, 2) void gemm_nt(
    const u16* __restrict__ A, const u16* __restrict__ W,
    const float* __restrict__ bias, const float* __restrict__ resid,
    void* __restrict__ Cout, void* __restrict__ Cout2, int N, int K) {
    __shared__ u16 Als[2][128 * 64];
    __shared__ u16 Bls[2][128 * 64];
    const int tid = threadIdx.x;
    const int l = tid & 63, w = tid >> 6;
    const int m0 = blockIdx.y * 128;
    const int n0 = blockIdx.x * 128;
    const int wr = (w >> 1) * 64, wc = (w & 1) * 64;
    const int lhi = l >> 4, l15 = l & 15, l7 = l & 7;

    f32x4 acc[4][4] = {};

    const int srow = l >> 3;
    const int scol = ((l & 7) * 8) ^ (srow << 3);

    auto stage = [&](int buf, int kt) {
#pragma unroll
        for (int i = 0; i < 4; ++i) {
            int cc = w * 4 + i;
            int grow = cc * 8 + srow;
            gload_lds16(&A[(size_t)(m0 + grow) * K + kt + scol],
                        &Als[buf][cc * 512]);
            gload_lds16(&W[(size_t)(n0 + grow) * K + kt + scol],
                        &Bls[buf][cc * 512]);
        }
    };

    auto compute = [&](int buf) {
#pragma unroll
        for (int kk = 0; kk < 2; ++kk) {
            const int koff = (kk * 32 + lhi * 8) ^ (l7 << 3);
            bf16x8 af[4], bfr[4];
#pragma unroll
            for (int m = 0; m < 4; ++m)
                af[m] = *reinterpret_cast<const bf16x8*>(
                    &Als[buf][(wr + m * 16 + l15) * 64 + koff]);
#pragma unroll
            for (int n = 0; n < 4; ++n)
                bfr[n] = *reinterpret_cast<const bf16x8*>(
                    &Bls[buf][(wc + n * 16 + l15) * 64 + koff]);
#pragma unroll
            for (int m = 0; m < 4; ++m)
#pragma unroll
                for (int n = 0; n < 4; ++n)
                    acc[m][n] = __builtin_amdgcn_mfma_f32_16x16x32_bf16(
                        af[m], bfr[n], acc[m][n], 0, 0, 0);
        }
    };

    stage(0, 0);
    asm volatile("s_waitcnt vmcnt(0)" ::: "memory");
    __builtin_amdgcn_s_barrier();

    for (int kt = 0; kt < K; kt += 128) {
        if (kt + 64 < K) stage(1, kt + 64);
        __builtin_amdgcn_sched_barrier(0);
        compute(0);
        asm volatile("s_waitcnt vmcnt(0)" ::: "memory");
        __builtin_amdgcn_s_barrier();
        if (kt + 128 < K) stage(0, kt + 128);
        __builtin_amdgcn_sched_barrier(0);
        compute(1);
        asm volatile("s_waitcnt vmcnt(0)" ::: "memory");
        __builtin_amdgcn_s_barrier();
    }

    int colg[4];
    float bv[4];
#pragma unroll
    for (int cn = 0; cn < 4; ++cn) {
        colg[cn] = n0 + wc + cn * 16 + l15;
        bv[cn] = bias[colg[cn]];
    }
#pragma unroll
    for (int am = 0; am < 4; ++am) {
        int rowg = m0 + wr + am * 16 + 4 * lhi;
#pragma unroll
        for (int cn = 0; cn < 4; ++cn) {
            float v[4];
#pragma unroll
            for (int r = 0; r < 4; ++r) {
                float t = acc[am][cn][r] + bv[cn];
                if constexpr (RELU) t = fmaxf(t, 0.f);
                if constexpr (RESID)
                    t += resid[(size_t)(rowg + r) * N + colg[cn]];
                v[r] = t;
            }
            if constexpr (OUTMODE == 0) {
                u16* o = (u16*)Cout;
#pragma unroll
                for (int r = 0; r < 4; ++r)
                    o[(size_t)(rowg + r) * N + colg[cn]] = f2b(v[r]);
            } else {
                float* o = (float*)Cout;
#pragma unroll
                for (int r = 0; r < 4; ++r)
                    o[(size_t)(rowg + r) * N + colg[cn]] = v[r];
            }
        }
    }
}

// ---------------------------------------------------------------------------
// Flash attention v9 (unchanged from round 9): K LDS (source-swizzled) +
// V8 LDS (one b128 B-frag), swapped QK^T (C1 pre-folded), clamped no-max
// softmax, PV 16x16x32, row-sum via MFMA(ones). grid 1024 (XCD-swizzled).
// ---------------------------------------------------------------------------
__global__ __launch_bounds__(256, 3) void attn_fwd(
    const u16* __restrict__ qk, const u16* __restrict__ v8,
    const int* __restrict__ mask, u16* __restrict__ out) {
    __shared__ u16 Kls[2][64 * 64];
    __shared__ u16 Vls[2][8 * 512];
    const int tid = threadIdx.x;
    const int l = tid & 63, w = tid >> 6;
    const int lhi = l >> 4, l15 = l & 15;
    const int lb = (blockIdx.x & 7) * 128 + (blockIdx.x >> 3);  // XCD swizzle
    const int qt = lb & 15, bh = lb >> 4;
    const int b = bh >> 3, h = bh & 7;
    const int q0 = qt * 128 + w * 32;

    const u16* Qb = qk + (size_t)b * SEQ * 1024 + h * 64;
    const u16* Kb = Qb + 512;
    const u16* Vb8 = v8 + (size_t)b * 1048576 + h * 512;
    const int* Mb = mask + b * SEQ;

    const int srow = l >> 3;
    const int scol = ((l & 7) ^ srow) << 3;

    bf16x8 qf[2][2];
#pragma unroll
    for (int g = 0; g < 2; ++g) {
        size_t qa = (size_t)(q0 + g * 16 + l15) * 1024 + lhi * 8;
        qf[g][0] = *reinterpret_cast<const bf16x8*>(&Qb[qa]);
        qf[g][1] = *reinterpret_cast<const bf16x8*>(&Qb[qa + 32]);
    }

    bf16x8 ones8;
#pragma unroll
    for (int i = 0; i < 8; ++i) ones8[i] = (__bf16)1.0f;

    int allone;
    {
        int acc = 1;
#pragma unroll
        for (int i = 0; i < 8; ++i) {
            int4 mm = *reinterpret_cast<const int4*>(&Mb[l * 32 + i * 4]);
            acc &= mm.x & mm.y & mm.z & mm.w;
        }
        allone = __all(acc == 1);
    }

    f32x4 oacc[2][4] = {};
    f32x4 osum[2] = {};

    auto stage = [&](int buf, int kv) {
#pragma unroll
        for (int i = 0; i < 2; ++i) {
            int cc = w * 2 + i;
            int row = cc * 8 + srow;
            gload_lds16(&Kb[(size_t)(kv + row) * 1024 + scol], &Kls[buf][cc * 512]);
            gload_lds16(&Vb8[(size_t)((kv >> 5) + (cc >> 2)) * 16384 +
                             (cc & 3) * 4096 + l * 8],
                        &Vls[buf][cc * 512]);
        }
    };

    const int sw = (l15 & 7) << 3;

    auto tile = [&](int buf, int kv, bool pf, int pbuf, int pkv) {
        if (pf) stage(pbuf, pkv);
        __builtin_amdgcn_sched_barrier(0);

        f32x4 sc[2][4];
        __builtin_amdgcn_s_setprio(1);
#pragma unroll
        for (int ks = 0; ks < 4; ++ks) {
            int krow = ks * 16 + l15;
            bf16x8 ka0 = *reinterpret_cast<const bf16x8*>(
                &Kls[buf][krow * 64 + ((lhi * 8) ^ sw)]);
            bf16x8 ka1 = *reinterpret_cast<const bf16x8*>(
                &Kls[buf][krow * 64 + ((32 + lhi * 8) ^ sw)]);
#pragma unroll
            for (int g = 0; g < 2; ++g) {
                f32x4 z = {};
                z = __builtin_amdgcn_mfma_f32_16x16x32_bf16(ka0, qf[g][0], z, 0, 0, 0);
                z = __builtin_amdgcn_mfma_f32_16x16x32_bf16(ka1, qf[g][1], z, 0, 0, 0);
                sc[g][ks] = z;
            }
        }
        __builtin_amdgcn_s_setprio(0);

        if (!allone) {
            int4 mm[4];
#pragma unroll
            for (int ks = 0; ks < 4; ++ks)
                mm[ks] = *reinterpret_cast<const int4*>(&Mb[kv + ks * 16 + 4 * lhi]);
#pragma unroll
            for (int ks = 0; ks < 4; ++ks) {
                if (mm[ks].x == 0) { sc[0][ks][0] = -3e38f; sc[1][ks][0] = -3e38f; }
                if (mm[ks].y == 0) { sc[0][ks][1] = -3e38f; sc[1][ks][1] = -3e38f; }
                if (mm[ks].z == 0) { sc[0][ks][2] = -3e38f; sc[1][ks][2] = -3e38f; }
                if (mm[ks].w == 0) { sc[0][ks][3] = -3e38f; sc[1][ks][3] = -3e38f; }
            }
        }

        u32x4 pku[2][2];
#pragma unroll
        for (int g = 0; g < 2; ++g) {
#pragma unroll
            for (int ks = 0; ks < 4; ++ks) {
                float p0 = ex2(fminf(sc[g][ks][0], 30.f));
                float p1 = ex2(fminf(sc[g][ks][1], 30.f));
                float p2 = ex2(fminf(sc[g][ks][2], 30.f));
                float p3 = ex2(fminf(sc[g][ks][3], 30.f));
                pku[g][ks >> 1][(ks & 1) * 2 + 0] = pack2(p0, p1);
                pku[g][ks >> 1][(ks & 1) * 2 + 1] = pack2(p2, p3);
            }
        }

        __builtin_amdgcn_s_setprio(1);
#pragma unroll
        for (int kp = 0; kp < 2; ++kp) {
#pragma unroll
            for (int dc = 0; dc < 4; ++dc) {
                bf16x8 vb8 = *reinterpret_cast<const bf16x8*>(
                    &Vls[buf][(kp * 4 + lhi) * 512 + (dc * 16 + l15) * 8]);
#pragma unroll
                for (int g = 0; g < 2; ++g)
                    oacc[g][dc] = __builtin_amdgcn_mfma_f32_16x16x32_bf16(
                        __builtin_bit_cast(bf16x8, pku[g][kp]), vb8, oacc[g][dc],
                        0, 0, 0);
            }
#pragma unroll
            for (int g = 0; g < 2; ++g)
                osum[g] = __builtin_amdgcn_mfma_f32_16x16x32_bf16(
                    __builtin_bit_cast(bf16x8, pku[g][kp]), ones8, osum[g],
                    0, 0, 0);
        }
        __builtin_amdgcn_s_setprio(0);

        asm volatile("s_waitcnt vmcnt(0)" ::: "memory");
        __builtin_amdgcn_s_barrier();
    };

    stage(0, 0);
    asm volatile("s_waitcnt vmcnt(0)" ::: "memory");
    __builtin_amdgcn_s_barrier();

    for (int tt = 0; tt < 16; ++tt) {
        const int base = tt * 128;
        tile(0, base, true, 1, base + 64);
        tile(1, base + 64, tt < 15, 0, base + 128);
    }

#pragma unroll
    for (int g = 0; g < 2; ++g) {
#pragma unroll
        for (int r = 0; r < 4; ++r) {
            float inv = 1.f / osum[g][r];
            size_t rowa =
                ((size_t)b * SEQ + q0 + g * 16 + 4 * lhi + r) * DMODEL + h * 64;
#pragma unroll
            for (int dc = 0; dc < 4; ++dc)
                out[rowa + dc * 16 + l15] = f2b(oacc[g][dc][r] * inv);
        }
    }
}

// ---------------------------------------------------------------------------
extern "C" void kernel_launch(void* const* d_in, const int* in_sizes, int n_in,
                              void* d_out, int out_size, void* d_ws,
                              size_t ws_size, hipStream_t stream) {
    const float* x = (const float*)d_in[0];
    const int* mask = (const int*)d_in[1];
    const float* w_q = (const float*)d_in[2];
    const float* b_q = (const float*)d_in[3];
    const float* w_k = (const float*)d_in[4];
    const float* b_k = (const float*)d_in[5];
    const float* w_v = (const float*)d_in[6];
    const float* b_v = (const float*)d_in[7];
    const float* w_o = (const float*)d_in[8];
    const float* b_o = (const float*)d_in[9];
    const float* w_1 = (const float*)d_in[10];
    const float* b_1 = (const float*)d_in[11];
    const float* w_2 = (const float*)d_in[12];
    const float* b_2 = (const float*)d_in[13];

    char* ws = (char*)d_ws;
    const size_t MB = 1024ull * 1024ull;
    u16* lnx = (u16*)(ws + 0);          // 16 MiB; reused as attn_out
    u16* qkb = (u16*)(ws + 16 * MB);    // 32 MiB [16,48): q|k interleaved rows
    u16* v8 = (u16*)(ws + 48 * MB);     // 16 MiB [48,64): (B,S/32,4,512,8)
    u16* lnx1 = (u16*)(ws + 16 * MB);   // after attn, qkb dead
    u16* hbuf = (u16*)(ws + 32 * MB);   // 64 MiB [32,96); qkb-hi, v8 dead
    u16* wqkv = (u16*)(ws + 96 * MB);   // [1536][512] (q|k|v rows contiguous)
    u16* wob = wqkv + 3 * 262144;
    u16* w1b = wqkv + 4 * 262144;
    u16* w2b = w1b + 1048576;
    float* bqkv = (float*)(w2b + 1048576);  // 1536 floats
    u16* attn_o = lnx;
    float* x1 = (float*)d_out;

    cast_weights<<<1536, 256, 0, stream>>>(
        w_q, w_k, w_v, w_o, w_1, w_2, wqkv, wqkv + 262144, wqkv + 2 * 262144,
        wob, w1b, w2b);
    concat_bias<<<6, 256, 0, stream>>>(b_q, b_k, b_v, bqkv);
    ln_rows<<<4096, 256, 0, stream>>>(x, lnx);

    gemm256<false, 3><<<dim3(6, 64), 512, 0, stream>>>(lnx, wqkv, bqkv, qkb,
                                                       v8, 1536, 512);
    attn_fwd<<<1024, 256, 0, stream>>>(qkb, v8, mask, attn_o);
    gemm_nt<false, true, 1><<<dim3(4, 128), 256, 0, stream>>>(
        attn_o, wob, b_o, x, x1, nullptr, 512, 512);
    ln_rows<<<4096, 256, 0, stream>>>(x1, lnx1);
    gemm256<true, 0><<<dim3(8, 64), 512, 0, stream>>>(lnx1, w1b, b_1, hbuf,
                                                      nullptr, 2048, 512);
    gemm_nt<false, true, 1><<<dim3(4, 128), 256, 0, stream>>>(
        hbuf, w2b, b_2, x1, (float*)d_out, nullptr, 512, 2048);
}

// Round 11
// 268.542 us; speedup vs baseline: 1.0113x; 1.0113x over previous
//
#include <hip/hip_runtime.h>
#include <hip/hip_bf16.h>

typedef unsigned short u16;
typedef __bf16 bf16x8 __attribute__((ext_vector_type(8)));
typedef unsigned int u32x4 __attribute__((ext_vector_type(4)));
typedef float f32x4 __attribute__((ext_vector_type(4)));

#define SEQ 2048
#define DMODEL 512
#define NHEAD 8
#define DFF 2048
#define NBATCH 8
#define MROWS (NBATCH * SEQ)

// 0.125 * log2(e): folded into w_q/b_q so attn softmax is exp2(s) directly
#define C1_FOLD 0.18033688f

__device__ __forceinline__ u16 f2b(float f) {
    __hip_bfloat16 h = __float2bfloat16(f);
    u16 u;
    __builtin_memcpy(&u, &h, 2);
    return u;
}

__device__ __forceinline__ unsigned int pack2(float a, float b) {
    float2 f{a, b};
    __hip_bfloat162 h = __float22bfloat162_rn(f);
    unsigned int u;
    __builtin_memcpy(&u, &h, 4);
    return u;
}

__device__ __forceinline__ float ex2(float x) {
#if __has_builtin(__builtin_amdgcn_exp2f)
    return __builtin_amdgcn_exp2f(x);
#else
    return exp2f(x);
#endif
}

// async global->LDS, 16B per lane. LDS dest must be wave-uniform base; lane i
// lands at base + i*16.
__device__ __forceinline__ void gload_lds16(const void* g, void* lds) {
    auto* gp = reinterpret_cast<const __attribute__((address_space(1))) unsigned int*>(
        reinterpret_cast<uintptr_t>(g));
    auto* lp = reinterpret_cast<__attribute__((address_space(3))) unsigned int*>(
        reinterpret_cast<uintptr_t>(lds));
    __builtin_amdgcn_global_load_lds(gp, lp, 16, 0, 0);
}

// ---------------------------------------------------------------------------
// Weight cast fp32 -> bf16 (6 matrices in one launch). w_q scaled by C1.
// ---------------------------------------------------------------------------
__global__ __launch_bounds__(256) void cast_weights(
    const float* __restrict__ w0, const float* __restrict__ w1,
    const float* __restrict__ w2, const float* __restrict__ w3,
    const float* __restrict__ w4, const float* __restrict__ w5,
    u16* __restrict__ d0, u16* __restrict__ d1, u16* __restrict__ d2,
    u16* __restrict__ d3, u16* __restrict__ d4, u16* __restrict__ d5) {
    int blk = blockIdx.x;
    const float* s;
    u16* d;
    int base;
    float sc = 1.0f;
    if (blk < 512) {
        int seg = blk >> 7, lb = blk & 127;
        s = seg == 0 ? w0 : seg == 1 ? w1 : seg == 2 ? w2 : w3;
        d = seg == 0 ? d0 : seg == 1 ? d1 : seg == 2 ? d2 : d3;
        base = lb * 2048;
        if (seg == 0) sc = C1_FOLD;
    } else if (blk < 1024) {
        s = w4; d = d4; base = (blk - 512) * 2048;
    } else {
        s = w5; d = d5; base = (blk - 1024) * 2048;
    }
    int i = base + threadIdx.x * 8;
    float4 a = *reinterpret_cast<const float4*>(s + i);
    float4 b = *reinterpret_cast<const float4*>(s + i + 4);
    ushort4 oa, ob;
    oa.x = f2b(a.x * sc); oa.y = f2b(a.y * sc);
    oa.z = f2b(a.z * sc); oa.w = f2b(a.w * sc);
    ob.x = f2b(b.x * sc); ob.y = f2b(b.y * sc);
    ob.z = f2b(b.z * sc); ob.w = f2b(b.w * sc);
    *reinterpret_cast<ushort4*>(d + i) = oa;
    *reinterpret_cast<ushort4*>(d + i + 4) = ob;
}

// concat b_q*C1 | b_k | b_v -> bqkv[1536]
__global__ __launch_bounds__(256) void concat_bias(const float* __restrict__ bq,
                                                   const float* __restrict__ bk,
                                                   const float* __restrict__ bv,
                                                   float* __restrict__ dst) {
    int i = blockIdx.x * 256 + threadIdx.x;
    float v = i < 512 ? bq[i] * C1_FOLD : (i < 1024 ? bk[i - 512] : bv[i - 1024]);
    dst[i] = v;
}

// ---------------------------------------------------------------------------
// LayerNorm (unbiased var, ddof=1), fp32 in -> bf16 out. 1 wave / 512-row.
// ---------------------------------------------------------------------------
__global__ __launch_bounds__(256) void ln_rows(const float* __restrict__ x,
                                               u16* __restrict__ out) {
    int row = blockIdx.x * 4 + (threadIdx.x >> 6);
    int l = threadIdx.x & 63;
    const float* xr = x + (size_t)row * DMODEL + l * 8;
    float4 a = *reinterpret_cast<const float4*>(xr);
    float4 b = *reinterpret_cast<const float4*>(xr + 4);
    float s = a.x + a.y + a.z + a.w + b.x + b.y + b.z + b.w;
    float q = a.x * a.x + a.y * a.y + a.z * a.z + a.w * a.w +
              b.x * b.x + b.y * b.y + b.z * b.z + b.w * b.w;
#pragma unroll
    for (int d = 32; d >= 1; d >>= 1) {
        s += __shfl_xor(s, d, 64);
        q += __shfl_xor(q, d, 64);
    }
    float mean = s * (1.f / 512.f);
    float var = (q - 512.f * mean * mean) * (1.f / 511.f);
    float rs = rsqrtf(var + 1e-6f);
    ushort4 o0, o1;
    o0.x = f2b((a.x - mean) * rs); o0.y = f2b((a.y - mean) * rs);
    o0.z = f2b((a.z - mean) * rs); o0.w = f2b((a.w - mean) * rs);
    o1.x = f2b((b.x - mean) * rs); o1.y = f2b((b.y - mean) * rs);
    o1.z = f2b((b.z - mean) * rs); o1.w = f2b((b.w - mean) * rs);
    u16* op = out + (size_t)row * DMODEL + l * 8;
    *reinterpret_cast<ushort4*>(op) = o0;
    *reinterpret_cast<ushort4*>(op + 4) = o1;
}

// ---------------------------------------------------------------------------
// GEMM: C[M,N] = A[M,K] @ W[N,K]^T, 2-phase double-buffered (proven).
// OUTMODE: 0 = bf16 row-major, 1 = fp32 row-major,
//          3 = fused QKV: cols <1024 -> qk buffer [M][1024]; cols >=1024 ->
//              V8 store (B, S/32, 4, 512, 8), key = kk*32 + hb*16 + s*4 + j.
// ---------------------------------------------------------------------------
template <bool RELU, bool RESID, int OUTMODE>
__global__ __launch_bounds__(256, 2) void gemm_nt(
    const u16* __restrict__ A, const u16* __restrict__ W,
    const float* __restrict__ bias, const float* __restrict__ resid,
    void* __restrict__ Cout, void* __restrict__ Cout2, int N, int K) {
    __shared__ u16 Als[2][128 * 64];
    __shared__ u16 Bls[2][128 * 64];
    const int tid = threadIdx.x;
    const int l = tid & 63, w = tid >> 6;
    const int m0 = blockIdx.y * 128;
    const int n0 = blockIdx.x * 128;
    const int wr = (w >> 1) * 64, wc = (w & 1) * 64;
    const int lhi = l >> 4, l15 = l & 15, l7 = l & 7;

    f32x4 acc[4][4] = {};

    const int srow = l >> 3;
    const int scol = ((l & 7) * 8) ^ (srow << 3);

    auto stage = [&](int buf, int kt) {
#pragma unroll
        for (int i = 0; i < 4; ++i) {
            int cc = w * 4 + i;
            int grow = cc * 8 + srow;
            gload_lds16(&A[(size_t)(m0 + grow) * K + kt + scol],
                        &Als[buf][cc * 512]);
            gload_lds16(&W[(size_t)(n0 + grow) * K + kt + scol],
                        &Bls[buf][cc * 512]);
        }
    };

    auto compute = [&](int buf) {
#pragma unroll
        for (int kk = 0; kk < 2; ++kk) {
            const int koff = (kk * 32 + lhi * 8) ^ (l7 << 3);
            bf16x8 af[4], bfr[4];
#pragma unroll
            for (int m = 0; m < 4; ++m)
                af[m] = *reinterpret_cast<const bf16x8*>(
                    &Als[buf][(wr + m * 16 + l15) * 64 + koff]);
#pragma unroll
            for (int n = 0; n < 4; ++n)
                bfr[n] = *reinterpret_cast<const bf16x8*>(
                    &Bls[buf][(wc + n * 16 + l15) * 64 + koff]);
#pragma unroll
            for (int m = 0; m < 4; ++m)
#pragma unroll
                for (int n = 0; n < 4; ++n)
                    acc[m][n] = __builtin_amdgcn_mfma_f32_16x16x32_bf16(
                        af[m], bfr[n], acc[m][n], 0, 0, 0);
        }
    };

    stage(0, 0);
    asm volatile("s_waitcnt vmcnt(0)" ::: "memory");
    __builtin_amdgcn_s_barrier();

    for (int kt = 0; kt < K; kt += 128) {
        if (kt + 64 < K) stage(1, kt + 64);
        __builtin_amdgcn_sched_barrier(0);
        compute(0);
        asm volatile("s_waitcnt vmcnt(0)" ::: "memory");
        __builtin_amdgcn_s_barrier();
        if (kt + 128 < K) stage(0, kt + 128);
        __builtin_amdgcn_sched_barrier(0);
        compute(1);
        asm volatile("s_waitcnt vmcnt(0)" ::: "memory");
        __builtin_amdgcn_s_barrier();
    }

    int colg[4];
    float bv[4];
#pragma unroll
    for (int cn = 0; cn < 4; ++cn) {
        colg[cn] = n0 + wc + cn * 16 + l15;
        bv[cn] = bias[colg[cn]];
    }
#pragma unroll
    for (int am = 0; am < 4; ++am) {
        int rowg = m0 + wr + am * 16 + 4 * lhi;
#pragma unroll
        for (int cn = 0; cn < 4; ++cn) {
            float v[4];
#pragma unroll
            for (int r = 0; r < 4; ++r) {
                float t = acc[am][cn][r] + bv[cn];
                if constexpr (RELU) t = fmaxf(t, 0.f);
                if constexpr (RESID)
                    t += resid[(size_t)(rowg + r) * N + colg[cn]];
                v[r] = t;
            }
            if constexpr (OUTMODE == 0) {
                u16* o = (u16*)Cout;
#pragma unroll
                for (int r = 0; r < 4; ++r)
                    o[(size_t)(rowg + r) * N + colg[cn]] = f2b(v[r]);
            } else if constexpr (OUTMODE == 1) {
                float* o = (float*)Cout;
#pragma unroll
                for (int r = 0; r < 4; ++r)
                    o[(size_t)(rowg + r) * N + colg[cn]] = v[r];
            } else {
                // fused QKV: n0 is block-uniform
                if (n0 < 1024) {
                    u16* o = (u16*)Cout;  // qk buffer [M][1024]
#pragma unroll
                    for (int r = 0; r < 4; ++r)
                        o[(size_t)(rowg + r) * 1024 + colg[cn]] = f2b(v[r]);
                } else {
                    // V8 (B, S/32, 4, 512, 8): 4 consecutive keys share
                    // (kk, hb, s), j = 0..3 -> one contiguous 8B store
                    u16* o = (u16*)Cout2;
                    int bb = rowg >> 11, sloc = rowg & 2047;  // sloc % 4 == 0
                    int dg = colg[cn] - 1024;
                    int kk = sloc >> 5, hb = (sloc >> 4) & 1, ss = (sloc >> 2) & 3;
                    ushort4 pk;
                    pk.x = f2b(v[0]); pk.y = f2b(v[1]);
                    pk.z = f2b(v[2]); pk.w = f2b(v[3]);
                    *reinterpret_cast<ushort4*>(
                        &o[(size_t)(bb * 64 + kk) * 16384 + ss * 4096 + dg * 8 +
                           hb * 4]) = pk;
                }
            }
        }
    }
}

// ---------------------------------------------------------------------------
// Flash attention v11: round-9 body (76 VGPR) at __launch_bounds__(256,4) —
// grid is exactly 4 blocks/CU; residency 4 removes the ceil(4/3) serial tail
// seen at (256,3) (Occupancy 25%). 76 VGPR < 128 cap -> no spill (tripwire:
// FETCH/WRITE balloon). K LDS (source-swizzled) + V8 LDS (one b128 B-frag),
// swapped QK^T (C1 pre-folded), clamped no-max softmax, PV 16x16x32,
// row-sum via MFMA(ones). grid 1024 (XCD-swizzled).
// ---------------------------------------------------------------------------
__global__ __launch_bounds__(256, 4) void attn_fwd(
    const u16* __restrict__ qk, const u16* __restrict__ v8,
    const int* __restrict__ mask, u16* __restrict__ out) {
    __shared__ u16 Kls[2][64 * 64];
    __shared__ u16 Vls[2][8 * 512];
    const int tid = threadIdx.x;
    const int l = tid & 63, w = tid >> 6;
    const int lhi = l >> 4, l15 = l & 15;
    const int lb = (blockIdx.x & 7) * 128 + (blockIdx.x >> 3);  // XCD swizzle
    const int qt = lb & 15, bh = lb >> 4;
    const int b = bh >> 3, h = bh & 7;
    const int q0 = qt * 128 + w * 32;

    const u16* Qb = qk + (size_t)b * SEQ * 1024 + h * 64;
    const u16* Kb = Qb + 512;
    const u16* Vb8 = v8 + (size_t)b * 1048576 + h * 512;
    const int* Mb = mask + b * SEQ;

    const int srow = l >> 3;
    const int scol = ((l & 7) ^ srow) << 3;

    bf16x8 qf[2][2];
#pragma unroll
    for (int g = 0; g < 2; ++g) {
        size_t qa = (size_t)(q0 + g * 16 + l15) * 1024 + lhi * 8;
        qf[g][0] = *reinterpret_cast<const bf16x8*>(&Qb[qa]);
        qf[g][1] = *reinterpret_cast<const bf16x8*>(&Qb[qa + 32]);
    }

    bf16x8 ones8;
#pragma unroll
    for (int i = 0; i < 8; ++i) ones8[i] = (__bf16)1.0f;

    int allone;
    {
        int acc = 1;
#pragma unroll
        for (int i = 0; i < 8; ++i) {
            int4 mm = *reinterpret_cast<const int4*>(&Mb[l * 32 + i * 4]);
            acc &= mm.x & mm.y & mm.z & mm.w;
        }
        allone = __all(acc == 1);
    }

    f32x4 oacc[2][4] = {};
    f32x4 osum[2] = {};

    auto stage = [&](int buf, int kv) {
#pragma unroll
        for (int i = 0; i < 2; ++i) {
            int cc = w * 2 + i;
            int row = cc * 8 + srow;
            gload_lds16(&Kb[(size_t)(kv + row) * 1024 + scol], &Kls[buf][cc * 512]);
            gload_lds16(&Vb8[(size_t)((kv >> 5) + (cc >> 2)) * 16384 +
                             (cc & 3) * 4096 + l * 8],
                        &Vls[buf][cc * 512]);
        }
    };

    const int sw = (l15 & 7) << 3;

    auto tile = [&](int buf, int kv, bool pf, int pbuf, int pkv) {
        if (pf) stage(pbuf, pkv);
        __builtin_amdgcn_sched_barrier(0);

        f32x4 sc[2][4];
        __builtin_amdgcn_s_setprio(1);
#pragma unroll
        for (int ks = 0; ks < 4; ++ks) {
            int krow = ks * 16 + l15;
            bf16x8 ka0 = *reinterpret_cast<const bf16x8*>(
                &Kls[buf][krow * 64 + ((lhi * 8) ^ sw)]);
            bf16x8 ka1 = *reinterpret_cast<const bf16x8*>(
                &Kls[buf][krow * 64 + ((32 + lhi * 8) ^ sw)]);
#pragma unroll
            for (int g = 0; g < 2; ++g) {
                f32x4 z = {};
                z = __builtin_amdgcn_mfma_f32_16x16x32_bf16(ka0, qf[g][0], z, 0, 0, 0);
                z = __builtin_amdgcn_mfma_f32_16x16x32_bf16(ka1, qf[g][1], z, 0, 0, 0);
                sc[g][ks] = z;
            }
        }
        __builtin_amdgcn_s_setprio(0);

        if (!allone) {
            int4 mm[4];
#pragma unroll
            for (int ks = 0; ks < 4; ++ks)
                mm[ks] = *reinterpret_cast<const int4*>(&Mb[kv + ks * 16 + 4 * lhi]);
#pragma unroll
            for (int ks = 0; ks < 4; ++ks) {
                if (mm[ks].x == 0) { sc[0][ks][0] = -3e38f; sc[1][ks][0] = -3e38f; }
                if (mm[ks].y == 0) { sc[0][ks][1] = -3e38f; sc[1][ks][1] = -3e38f; }
                if (mm[ks].z == 0) { sc[0][ks][2] = -3e38f; sc[1][ks][2] = -3e38f; }
                if (mm[ks].w == 0) { sc[0][ks][3] = -3e38f; sc[1][ks][3] = -3e38f; }
            }
        }

        u32x4 pku[2][2];
#pragma unroll
        for (int g = 0; g < 2; ++g) {
#pragma unroll
            for (int ks = 0; ks < 4; ++ks) {
                float p0 = ex2(fminf(sc[g][ks][0], 30.f));
                float p1 = ex2(fminf(sc[g][ks][1], 30.f));
                float p2 = ex2(fminf(sc[g][ks][2], 30.f));
                float p3 = ex2(fminf(sc[g][ks][3], 30.f));
                pku[g][ks >> 1][(ks & 1) * 2 + 0] = pack2(p0, p1);
                pku[g][ks >> 1][(ks & 1) * 2 + 1] = pack2(p2, p3);
            }
        }

        __builtin_amdgcn_s_setprio(1);
#pragma unroll
        for (int kp = 0; kp < 2; ++kp) {
#pragma unroll
            for (int dc = 0; dc < 4; ++dc) {
                bf16x8 vb8 = *reinterpret_cast<const bf16x8*>(
                    &Vls[buf][(kp * 4 + lhi) * 512 + (dc * 16 + l15) * 8]);
#pragma unroll
                for (int g = 0; g < 2; ++g)
                    oacc[g][dc] = __builtin_amdgcn_mfma_f32_16x16x32_bf16(
                        __builtin_bit_cast(bf16x8, pku[g][kp]), vb8, oacc[g][dc],
                        0, 0, 0);
            }
#pragma unroll
            for (int g = 0; g < 2; ++g)
                osum[g] = __builtin_amdgcn_mfma_f32_16x16x32_bf16(
                    __builtin_bit_cast(bf16x8, pku[g][kp]), ones8, osum[g],
                    0, 0, 0);
        }
        __builtin_amdgcn_s_setprio(0);

        asm volatile("s_waitcnt vmcnt(0)" ::: "memory");
        __builtin_amdgcn_s_barrier();
    };

    stage(0, 0);
    asm volatile("s_waitcnt vmcnt(0)" ::: "memory");
    __builtin_amdgcn_s_barrier();

    for (int tt = 0; tt < 16; ++tt) {
        const int base = tt * 128;
        tile(0, base, true, 1, base + 64);
        tile(1, base + 64, tt < 15, 0, base + 128);
    }

#pragma unroll
    for (int g = 0; g < 2; ++g) {
#pragma unroll
        for (int r = 0; r < 4; ++r) {
            float inv = 1.f / osum[g][r];
            size_t rowa =
                ((size_t)b * SEQ + q0 + g * 16 + 4 * lhi + r) * DMODEL + h * 64;
#pragma unroll
            for (int dc = 0; dc < 4; ++dc)
                out[rowa + dc * 16 + l15] = f2b(oacc[g][dc][r] * inv);
        }
    }
}

// ---------------------------------------------------------------------------
extern "C" void kernel_launch(void* const* d_in, const int* in_sizes, int n_in,
                              void* d_out, int out_size, void* d_ws,
                              size_t ws_size, hipStream_t stream) {
    const float* x = (const float*)d_in[0];
    const int* mask = (const int*)d_in[1];
    const float* w_q = (const float*)d_in[2];
    const float* b_q = (const float*)d_in[3];
    const float* w_k = (const float*)d_in[4];
    const float* b_k = (const float*)d_in[5];
    const float* w_v = (const float*)d_in[6];
    const float* b_v = (const float*)d_in[7];
    const float* w_o = (const float*)d_in[8];
    const float* b_o = (const float*)d_in[9];
    const float* w_1 = (const float*)d_in[10];
    const float* b_1 = (const float*)d_in[11];
    const float* w_2 = (const float*)d_in[12];
    const float* b_2 = (const float*)d_in[13];

    char* ws = (char*)d_ws;
    const size_t MB = 1024ull * 1024ull;
    u16* lnx = (u16*)(ws + 0);          // 16 MiB; reused as attn_out
    u16* qkb = (u16*)(ws + 16 * MB);    // 32 MiB [16,48): q|k interleaved rows
    u16* v8 = (u16*)(ws + 48 * MB);     // 16 MiB [48,64): (B,S/32,4,512,8)
    u16* lnx1 = (u16*)(ws + 16 * MB);   // after attn, qkb dead
    u16* hbuf = (u16*)(ws + 32 * MB);   // 64 MiB [32,96); qkb-hi, v8 dead
    u16* wqkv = (u16*)(ws + 96 * MB);   // [1536][512] (q|k|v rows contiguous)
    u16* wob = wqkv + 3 * 262144;
    u16* w1b = wqkv + 4 * 262144;
    u16* w2b = w1b + 1048576;
    float* bqkv = (float*)(w2b + 1048576);  // 1536 floats
    u16* attn_o = lnx;
    float* x1 = (float*)d_out;

    cast_weights<<<1536, 256, 0, stream>>>(
        w_q, w_k, w_v, w_o, w_1, w_2, wqkv, wqkv + 262144, wqkv + 2 * 262144,
        wob, w1b, w2b);
    concat_bias<<<6, 256, 0, stream>>>(b_q, b_k, b_v, bqkv);
    ln_rows<<<4096, 256, 0, stream>>>(x, lnx);

    dim3 g12(12, 128), g4(4, 128), g16(16, 128);
    gemm_nt<false, false, 3><<<g12, 256, 0, stream>>>(lnx, wqkv, bqkv, nullptr,
                                                      qkb, v8, 1536, 512);
    attn_fwd<<<1024, 256, 0, stream>>>(qkb, v8, mask, attn_o);
    gemm_nt<false, true, 1><<<g4, 256, 0, stream>>>(attn_o, wob, b_o, x, x1,
                                                    nullptr, 512, 512);
    ln_rows<<<4096, 256, 0, stream>>>(x1, lnx1);
    gemm_nt<true, false, 0><<<g16, 256, 0, stream>>>(lnx1, w1b, b_1, nullptr,
                                                     hbuf, nullptr, 2048, 512);
    gemm_nt<false, true, 1><<<g4, 256, 0, stream>>>(hbuf, w2b, b_2, x1,
                                                    (float*)d_out, nullptr,
                                                    512, 2048);
}

// Round 12
// 256.007 us; speedup vs baseline: 1.0608x; 1.0490x over previous
//
#include <hip/hip_runtime.h>
#include <hip/hip_bf16.h>

typedef unsigned short u16;
typedef __bf16 bf16x8 __attribute__((ext_vector_type(8)));
typedef unsigned int u32x4 __attribute__((ext_vector_type(4)));
typedef float f32x4 __attribute__((ext_vector_type(4)));

#define SEQ 2048
#define DMODEL 512
#define NHEAD 8
#define DFF 2048
#define NBATCH 8
#define MROWS (NBATCH * SEQ)

// 0.125 * log2(e): folded into w_q/b_q so attn softmax is exp2(s) directly
#define C1_FOLD 0.18033688f

__device__ __forceinline__ u16 f2b(float f) {
    __hip_bfloat16 h = __float2bfloat16(f);
    u16 u;
    __builtin_memcpy(&u, &h, 2);
    return u;
}

__device__ __forceinline__ unsigned int pack2(float a, float b) {
    float2 f{a, b};
    __hip_bfloat162 h = __float22bfloat162_rn(f);
    unsigned int u;
    __builtin_memcpy(&u, &h, 4);
    return u;
}

__device__ __forceinline__ float ex2(float x) {
#if __has_builtin(__builtin_amdgcn_exp2f)
    return __builtin_amdgcn_exp2f(x);
#else
    return exp2f(x);
#endif
}

// async global->LDS, 16B per lane. LDS dest must be wave-uniform base; lane i
// lands at base + i*16.
__device__ __forceinline__ void gload_lds16(const void* g, void* lds) {
    auto* gp = reinterpret_cast<const __attribute__((address_space(1))) unsigned int*>(
        reinterpret_cast<uintptr_t>(g));
    auto* lp = reinterpret_cast<__attribute__((address_space(3))) unsigned int*>(
        reinterpret_cast<uintptr_t>(lds));
    __builtin_amdgcn_global_load_lds(gp, lp, 16, 0, 0);
}

// ---------------------------------------------------------------------------
// Weight cast fp32 -> bf16 (6 matrices in one launch). w_q scaled by C1.
// ---------------------------------------------------------------------------
__global__ __launch_bounds__(256) void cast_weights(
    const float* __restrict__ w0, const float* __restrict__ w1,
    const float* __restrict__ w2, const float* __restrict__ w3,
    const float* __restrict__ w4, const float* __restrict__ w5,
    u16* __restrict__ d0, u16* __restrict__ d1, u16* __restrict__ d2,
    u16* __restrict__ d3, u16* __restrict__ d4, u16* __restrict__ d5) {
    int blk = blockIdx.x;
    const float* s;
    u16* d;
    int base;
    float sc = 1.0f;
    if (blk < 512) {
        int seg = blk >> 7, lb = blk & 127;
        s = seg == 0 ? w0 : seg == 1 ? w1 : seg == 2 ? w2 : w3;
        d = seg == 0 ? d0 : seg == 1 ? d1 : seg == 2 ? d2 : d3;
        base = lb * 2048;
        if (seg == 0) sc = C1_FOLD;
    } else if (blk < 1024) {
        s = w4; d = d4; base = (blk - 512) * 2048;
    } else {
        s = w5; d = d5; base = (blk - 1024) * 2048;
    }
    int i = base + threadIdx.x * 8;
    float4 a = *reinterpret_cast<const float4*>(s + i);
    float4 b = *reinterpret_cast<const float4*>(s + i + 4);
    ushort4 oa, ob;
    oa.x = f2b(a.x * sc); oa.y = f2b(a.y * sc);
    oa.z = f2b(a.z * sc); oa.w = f2b(a.w * sc);
    ob.x = f2b(b.x * sc); ob.y = f2b(b.y * sc);
    ob.z = f2b(b.z * sc); ob.w = f2b(b.w * sc);
    *reinterpret_cast<ushort4*>(d + i) = oa;
    *reinterpret_cast<ushort4*>(d + i + 4) = ob;
}

// concat b_q*C1 | b_k | b_v -> bqkv[1536]
__global__ __launch_bounds__(256) void concat_bias(const float* __restrict__ bq,
                                                   const float* __restrict__ bk,
                                                   const float* __restrict__ bv,
                                                   float* __restrict__ dst) {
    int i = blockIdx.x * 256 + threadIdx.x;
    float v = i < 512 ? bq[i] * C1_FOLD : (i < 1024 ? bk[i - 512] : bv[i - 1024]);
    dst[i] = v;
}

// ---------------------------------------------------------------------------
// LayerNorm (unbiased var, ddof=1), fp32 in -> bf16 out. 1 wave / 512-row.
// ---------------------------------------------------------------------------
__global__ __launch_bounds__(256) void ln_rows(const float* __restrict__ x,
                                               u16* __restrict__ out) {
    int row = blockIdx.x * 4 + (threadIdx.x >> 6);
    int l = threadIdx.x & 63;
    const float* xr = x + (size_t)row * DMODEL + l * 8;
    float4 a = *reinterpret_cast<const float4*>(xr);
    float4 b = *reinterpret_cast<const float4*>(xr + 4);
    float s = a.x + a.y + a.z + a.w + b.x + b.y + b.z + b.w;
    float q = a.x * a.x + a.y * a.y + a.z * a.z + a.w * a.w +
              b.x * b.x + b.y * b.y + b.z * b.z + b.w * b.w;
#pragma unroll
    for (int d = 32; d >= 1; d >>= 1) {
        s += __shfl_xor(s, d, 64);
        q += __shfl_xor(q, d, 64);
    }
    float mean = s * (1.f / 512.f);
    float var = (q - 512.f * mean * mean) * (1.f / 511.f);
    float rs = rsqrtf(var + 1e-6f);
    ushort4 o0, o1;
    o0.x = f2b((a.x - mean) * rs); o0.y = f2b((a.y - mean) * rs);
    o0.z = f2b((a.z - mean) * rs); o0.w = f2b((a.w - mean) * rs);
    o1.x = f2b((b.x - mean) * rs); o1.y = f2b((b.y - mean) * rs);
    o1.z = f2b((b.z - mean) * rs); o1.w = f2b((b.w - mean) * rs);
    u16* op = out + (size_t)row * DMODEL + l * 8;
    *reinterpret_cast<ushort4*>(op) = o0;
    *reinterpret_cast<ushort4*>(op + 4) = o1;
}

// ---------------------------------------------------------------------------
// GEMM: C[M,N] = A[M,K] @ W[N,K]^T, 2-phase double-buffered (proven).
// 1D grid + chunked XCD swizzle: lb = (bid&7)*(nwg/8) + bid>>3 so each XCD
// owns contiguous M-panels -> A-panel fetched once per XCD, then L2-hits.
// NX = N-tiles (compile-time). OUTMODE: 0 = bf16 row-major, 1 = fp32
// row-major, 3 = fused QKV (qk [M][1024] / V8 (B,S/32,4,512,8)).
// ---------------------------------------------------------------------------
template <bool RELU, bool RESID, int OUTMODE, int NX>
__global__ __launch_bounds__(256, 2) void gemm_nt(
    const u16* __restrict__ A, const u16* __restrict__ W,
    const float* __restrict__ bias, const float* __restrict__ resid,
    void* __restrict__ Cout, void* __restrict__ Cout2, int N, int K) {
    __shared__ u16 Als[2][128 * 64];
    __shared__ u16 Bls[2][128 * 64];
    const int tid = threadIdx.x;
    const int l = tid & 63, w = tid >> 6;
    const int nwg = gridDim.x;
    const int lb = (blockIdx.x & 7) * (nwg >> 3) + (blockIdx.x >> 3);
    const int m0 = (lb / NX) * 128;
    const int n0 = (lb % NX) * 128;
    const int wr = (w >> 1) * 64, wc = (w & 1) * 64;
    const int lhi = l >> 4, l15 = l & 15, l7 = l & 7;

    f32x4 acc[4][4] = {};

    const int srow = l >> 3;
    const int scol = ((l & 7) * 8) ^ (srow << 3);

    auto stage = [&](int buf, int kt) {
#pragma unroll
        for (int i = 0; i < 4; ++i) {
            int cc = w * 4 + i;
            int grow = cc * 8 + srow;
            gload_lds16(&A[(size_t)(m0 + grow) * K + kt + scol],
                        &Als[buf][cc * 512]);
            gload_lds16(&W[(size_t)(n0 + grow) * K + kt + scol],
                        &Bls[buf][cc * 512]);
        }
    };

    auto compute = [&](int buf) {
#pragma unroll
        for (int kk = 0; kk < 2; ++kk) {
            const int koff = (kk * 32 + lhi * 8) ^ (l7 << 3);
            bf16x8 af[4], bfr[4];
#pragma unroll
            for (int m = 0; m < 4; ++m)
                af[m] = *reinterpret_cast<const bf16x8*>(
                    &Als[buf][(wr + m * 16 + l15) * 64 + koff]);
#pragma unroll
            for (int n = 0; n < 4; ++n)
                bfr[n] = *reinterpret_cast<const bf16x8*>(
                    &Bls[buf][(wc + n * 16 + l15) * 64 + koff]);
#pragma unroll
            for (int m = 0; m < 4; ++m)
#pragma unroll
                for (int n = 0; n < 4; ++n)
                    acc[m][n] = __builtin_amdgcn_mfma_f32_16x16x32_bf16(
                        af[m], bfr[n], acc[m][n], 0, 0, 0);
        }
    };

    stage(0, 0);
    asm volatile("s_waitcnt vmcnt(0)" ::: "memory");
    __builtin_amdgcn_s_barrier();

    for (int kt = 0; kt < K; kt += 128) {
        if (kt + 64 < K) stage(1, kt + 64);
        __builtin_amdgcn_sched_barrier(0);
        compute(0);
        asm volatile("s_waitcnt vmcnt(0)" ::: "memory");
        __builtin_amdgcn_s_barrier();
        if (kt + 128 < K) stage(0, kt + 128);
        __builtin_amdgcn_sched_barrier(0);
        compute(1);
        asm volatile("s_waitcnt vmcnt(0)" ::: "memory");
        __builtin_amdgcn_s_barrier();
    }

    int colg[4];
    float bv[4];
#pragma unroll
    for (int cn = 0; cn < 4; ++cn) {
        colg[cn] = n0 + wc + cn * 16 + l15;
        bv[cn] = bias[colg[cn]];
    }
#pragma unroll
    for (int am = 0; am < 4; ++am) {
        int rowg = m0 + wr + am * 16 + 4 * lhi;
#pragma unroll
        for (int cn = 0; cn < 4; ++cn) {
            float v[4];
#pragma unroll
            for (int r = 0; r < 4; ++r) {
                float t = acc[am][cn][r] + bv[cn];
                if constexpr (RELU) t = fmaxf(t, 0.f);
                if constexpr (RESID)
                    t += resid[(size_t)(rowg + r) * N + colg[cn]];
                v[r] = t;
            }
            if constexpr (OUTMODE == 0) {
                u16* o = (u16*)Cout;
#pragma unroll
                for (int r = 0; r < 4; ++r)
                    o[(size_t)(rowg + r) * N + colg[cn]] = f2b(v[r]);
            } else if constexpr (OUTMODE == 1) {
                float* o = (float*)Cout;
#pragma unroll
                for (int r = 0; r < 4; ++r)
                    o[(size_t)(rowg + r) * N + colg[cn]] = v[r];
            } else {
                // fused QKV: n0 is block-uniform
                if (n0 < 1024) {
                    u16* o = (u16*)Cout;  // qk buffer [M][1024]
#pragma unroll
                    for (int r = 0; r < 4; ++r)
                        o[(size_t)(rowg + r) * 1024 + colg[cn]] = f2b(v[r]);
                } else {
                    // V8 (B, S/32, 4, 512, 8): 4 consecutive keys share
                    // (kk, hb, s), j = 0..3 -> one contiguous 8B store
                    u16* o = (u16*)Cout2;
                    int bb = rowg >> 11, sloc = rowg & 2047;  // sloc % 4 == 0
                    int dg = colg[cn] - 1024;
                    int kk = sloc >> 5, hb = (sloc >> 4) & 1, ss = (sloc >> 2) & 3;
                    ushort4 pk;
                    pk.x = f2b(v[0]); pk.y = f2b(v[1]);
                    pk.z = f2b(v[2]); pk.w = f2b(v[3]);
                    *reinterpret_cast<ushort4*>(
                        &o[(size_t)(bb * 64 + kk) * 16384 + ss * 4096 + dg * 8 +
                           hb * 4]) = pk;
                }
            }
        }
    }
}

// ---------------------------------------------------------------------------
// Flash attention (unchanged from round 11): K LDS (source-swizzled) +
// V8 LDS (one b128 B-frag), swapped QK^T (C1 pre-folded), clamped no-max
// softmax, PV 16x16x32, row-sum via MFMA(ones). grid 1024 (XCD-swizzled).
// ---------------------------------------------------------------------------
__global__ __launch_bounds__(256, 4) void attn_fwd(
    const u16* __restrict__ qk, const u16* __restrict__ v8,
    const int* __restrict__ mask, u16* __restrict__ out) {
    __shared__ u16 Kls[2][64 * 64];
    __shared__ u16 Vls[2][8 * 512];
    const int tid = threadIdx.x;
    const int l = tid & 63, w = tid >> 6;
    const int lhi = l >> 4, l15 = l & 15;
    const int lb = (blockIdx.x & 7) * 128 + (blockIdx.x >> 3);  // XCD swizzle
    const int qt = lb & 15, bh = lb >> 4;
    const int b = bh >> 3, h = bh & 7;
    const int q0 = qt * 128 + w * 32;

    const u16* Qb = qk + (size_t)b * SEQ * 1024 + h * 64;
    const u16* Kb = Qb + 512;
    const u16* Vb8 = v8 + (size_t)b * 1048576 + h * 512;
    const int* Mb = mask + b * SEQ;

    const int srow = l >> 3;
    const int scol = ((l & 7) ^ srow) << 3;

    bf16x8 qf[2][2];
#pragma unroll
    for (int g = 0; g < 2; ++g) {
        size_t qa = (size_t)(q0 + g * 16 + l15) * 1024 + lhi * 8;
        qf[g][0] = *reinterpret_cast<const bf16x8*>(&Qb[qa]);
        qf[g][1] = *reinterpret_cast<const bf16x8*>(&Qb[qa + 32]);
    }

    bf16x8 ones8;
#pragma unroll
    for (int i = 0; i < 8; ++i) ones8[i] = (__bf16)1.0f;

    int allone;
    {
        int acc = 1;
#pragma unroll
        for (int i = 0; i < 8; ++i) {
            int4 mm = *reinterpret_cast<const int4*>(&Mb[l * 32 + i * 4]);
            acc &= mm.x & mm.y & mm.z & mm.w;
        }
        allone = __all(acc == 1);
    }

    f32x4 oacc[2][4] = {};
    f32x4 osum[2] = {};

    auto stage = [&](int buf, int kv) {
#pragma unroll
        for (int i = 0; i < 2; ++i) {
            int cc = w * 2 + i;
            int row = cc * 8 + srow;
            gload_lds16(&Kb[(size_t)(kv + row) * 1024 + scol], &Kls[buf][cc * 512]);
            gload_lds16(&Vb8[(size_t)((kv >> 5) + (cc >> 2)) * 16384 +
                             (cc & 3) * 4096 + l * 8],
                        &Vls[buf][cc * 512]);
        }
    };

    const int sw = (l15 & 7) << 3;

    auto tile = [&](int buf, int kv, bool pf, int pbuf, int pkv) {
        if (pf) stage(pbuf, pkv);
        __builtin_amdgcn_sched_barrier(0);

        f32x4 sc[2][4];
        __builtin_amdgcn_s_setprio(1);
#pragma unroll
        for (int ks = 0; ks < 4; ++ks) {
            int krow = ks * 16 + l15;
            bf16x8 ka0 = *reinterpret_cast<const bf16x8*>(
                &Kls[buf][krow * 64 + ((lhi * 8) ^ sw)]);
            bf16x8 ka1 = *reinterpret_cast<const bf16x8*>(
                &Kls[buf][krow * 64 + ((32 + lhi * 8) ^ sw)]);
#pragma unroll
            for (int g = 0; g < 2; ++g) {
                f32x4 z = {};
                z = __builtin_amdgcn_mfma_f32_16x16x32_bf16(ka0, qf[g][0], z, 0, 0, 0);
                z = __builtin_amdgcn_mfma_f32_16x16x32_bf16(ka1, qf[g][1], z, 0, 0, 0);
                sc[g][ks] = z;
            }
        }
        __builtin_amdgcn_s_setprio(0);

        if (!allone) {
            int4 mm[4];
#pragma unroll
            for (int ks = 0; ks < 4; ++ks)
                mm[ks] = *reinterpret_cast<const int4*>(&Mb[kv + ks * 16 + 4 * lhi]);
#pragma unroll
            for (int ks = 0; ks < 4; ++ks) {
                if (mm[ks].x == 0) { sc[0][ks][0] = -3e38f; sc[1][ks][0] = -3e38f; }
                if (mm[ks].y == 0) { sc[0][ks][1] = -3e38f; sc[1][ks][1] = -3e38f; }
                if (mm[ks].z == 0) { sc[0][ks][2] = -3e38f; sc[1][ks][2] = -3e38f; }
                if (mm[ks].w == 0) { sc[0][ks][3] = -3e38f; sc[1][ks][3] = -3e38f; }
            }
        }

        u32x4 pku[2][2];
#pragma unroll
        for (int g = 0; g < 2; ++g) {
#pragma unroll
            for (int ks = 0; ks < 4; ++ks) {
                float p0 = ex2(fminf(sc[g][ks][0], 30.f));
                float p1 = ex2(fminf(sc[g][ks][1], 30.f));
                float p2 = ex2(fminf(sc[g][ks][2], 30.f));
                float p3 = ex2(fminf(sc[g][ks][3], 30.f));
                pku[g][ks >> 1][(ks & 1) * 2 + 0] = pack2(p0, p1);
                pku[g][ks >> 1][(ks & 1) * 2 + 1] = pack2(p2, p3);
            }
        }

        __builtin_amdgcn_s_setprio(1);
#pragma unroll
        for (int kp = 0; kp < 2; ++kp) {
#pragma unroll
            for (int dc = 0; dc < 4; ++dc) {
                bf16x8 vb8 = *reinterpret_cast<const bf16x8*>(
                    &Vls[buf][(kp * 4 + lhi) * 512 + (dc * 16 + l15) * 8]);
#pragma unroll
                for (int g = 0; g < 2; ++g)
                    oacc[g][dc] = __builtin_amdgcn_mfma_f32_16x16x32_bf16(
                        __builtin_bit_cast(bf16x8, pku[g][kp]), vb8, oacc[g][dc],
                        0, 0, 0);
            }
#pragma unroll
            for (int g = 0; g < 2; ++g)
                osum[g] = __builtin_amdgcn_mfma_f32_16x16x32_bf16(
                    __builtin_bit_cast(bf16x8, pku[g][kp]), ones8, osum[g],
                    0, 0, 0);
        }
        __builtin_amdgcn_s_setprio(0);

        asm volatile("s_waitcnt vmcnt(0)" ::: "memory");
        __builtin_amdgcn_s_barrier();
    };

    stage(0, 0);
    asm volatile("s_waitcnt vmcnt(0)" ::: "memory");
    __builtin_amdgcn_s_barrier();

    for (int tt = 0; tt < 16; ++tt) {
        const int base = tt * 128;
        tile(0, base, true, 1, base + 64);
        tile(1, base + 64, tt < 15, 0, base + 128);
    }

#pragma unroll
    for (int g = 0; g < 2; ++g) {
#pragma unroll
        for (int r = 0; r < 4; ++r) {
            float inv = 1.f / osum[g][r];
            size_t rowa =
                ((size_t)b * SEQ + q0 + g * 16 + 4 * lhi + r) * DMODEL + h * 64;
#pragma unroll
            for (int dc = 0; dc < 4; ++dc)
                out[rowa + dc * 16 + l15] = f2b(oacc[g][dc][r] * inv);
        }
    }
}

// ---------------------------------------------------------------------------
extern "C" void kernel_launch(void* const* d_in, const int* in_sizes, int n_in,
                              void* d_out, int out_size, void* d_ws,
                              size_t ws_size, hipStream_t stream) {
    const float* x = (const float*)d_in[0];
    const int* mask = (const int*)d_in[1];
    const float* w_q = (const float*)d_in[2];
    const float* b_q = (const float*)d_in[3];
    const float* w_k = (const float*)d_in[4];
    const float* b_k = (const float*)d_in[5];
    const float* w_v = (const float*)d_in[6];
    const float* b_v = (const float*)d_in[7];
    const float* w_o = (const float*)d_in[8];
    const float* b_o = (const float*)d_in[9];
    const float* w_1 = (const float*)d_in[10];
    const float* b_1 = (const float*)d_in[11];
    const float* w_2 = (const float*)d_in[12];
    const float* b_2 = (const float*)d_in[13];

    char* ws = (char*)d_ws;
    const size_t MB = 1024ull * 1024ull;
    u16* lnx = (u16*)(ws + 0);          // 16 MiB; reused as attn_out
    u16* qkb = (u16*)(ws + 16 * MB);    // 32 MiB [16,48): q|k interleaved rows
    u16* v8 = (u16*)(ws + 48 * MB);     // 16 MiB [48,64): (B,S/32,4,512,8)
    u16* lnx1 = (u16*)(ws + 16 * MB);   // after attn, qkb dead
    u16* hbuf = (u16*)(ws + 32 * MB);   // 64 MiB [32,96); qkb-hi, v8 dead
    u16* wqkv = (u16*)(ws + 96 * MB);   // [1536][512] (q|k|v rows contiguous)
    u16* wob = wqkv + 3 * 262144;
    u16* w1b = wqkv + 4 * 262144;
    u16* w2b = w1b + 1048576;
    float* bqkv = (float*)(w2b + 1048576);  // 1536 floats
    u16* attn_o = lnx;
    float* x1 = (float*)d_out;

    cast_weights<<<1536, 256, 0, stream>>>(
        w_q, w_k, w_v, w_o, w_1, w_2, wqkv, wqkv + 262144, wqkv + 2 * 262144,
        wob, w1b, w2b);
    concat_bias<<<6, 256, 0, stream>>>(b_q, b_k, b_v, bqkv);
    ln_rows<<<4096, 256, 0, stream>>>(x, lnx);

    gemm_nt<false, false, 3, 12><<<1536, 256, 0, stream>>>(
        lnx, wqkv, bqkv, nullptr, qkb, v8, 1536, 512);
    attn_fwd<<<1024, 256, 0, stream>>>(qkb, v8, mask, attn_o);
    gemm_nt<false, true, 1, 4><<<512, 256, 0, stream>>>(
        attn_o, wob, b_o, x, x1, nullptr, 512, 512);
    ln_rows<<<4096, 256, 0, stream>>>(x1, lnx1);
    gemm_nt<true, false, 0, 16><<<2048, 256, 0, stream>>>(
        lnx1, w1b, b_1, nullptr, hbuf, nullptr, 2048, 512);
    gemm_nt<false, true, 1, 4><<<512, 256, 0, stream>>>(
        hbuf, w2b, b_2, x1, (float*)d_out, nullptr, 512, 2048);
}

// Round 13
// 255.137 us; speedup vs baseline: 1.0644x; 1.0034x over previous
//
#include <hip/hip_runtime.h>
#include <hip/hip_bf16.h>

typedef unsigned short u16;
typedef __bf16 bf16x8 __attribute__((ext_vector_type(8)));
typedef unsigned int u32x4 __attribute__((ext_vector_type(4)));
typedef float f32x4 __attribute__((ext_vector_type(4)));

#define SEQ 2048
#define DMODEL 512
#define NHEAD 8
#define DFF 2048
#define NBATCH 8
#define MROWS (NBATCH * SEQ)

// 0.125 * log2(e): folded into w_q/b_q so attn softmax is exp2(s) directly
#define C1_FOLD 0.18033688f

__device__ __forceinline__ u16 f2b(float f) {
    __hip_bfloat16 h = __float2bfloat16(f);
    u16 u;
    __builtin_memcpy(&u, &h, 2);
    return u;
}

__device__ __forceinline__ unsigned int pack2(float a, float b) {
    float2 f{a, b};
    __hip_bfloat162 h = __float22bfloat162_rn(f);
    unsigned int u;
    __builtin_memcpy(&u, &h, 4);
    return u;
}

__device__ __forceinline__ float ex2(float x) {
#if __has_builtin(__builtin_amdgcn_exp2f)
    return __builtin_amdgcn_exp2f(x);
#else
    return exp2f(x);
#endif
}

// async global->LDS, 16B per lane. LDS dest must be wave-uniform base; lane i
// lands at base + i*16.
__device__ __forceinline__ void gload_lds16(const void* g, void* lds) {
    auto* gp = reinterpret_cast<const __attribute__((address_space(1))) unsigned int*>(
        reinterpret_cast<uintptr_t>(g));
    auto* lp = reinterpret_cast<__attribute__((address_space(3))) unsigned int*>(
        reinterpret_cast<uintptr_t>(lds));
    __builtin_amdgcn_global_load_lds(gp, lp, 16, 0, 0);
}

// ---------------------------------------------------------------------------
// Weight cast fp32 -> bf16 (6 matrices in one launch). w_q scaled by C1.
// ---------------------------------------------------------------------------
__global__ __launch_bounds__(256) void cast_weights(
    const float* __restrict__ w0, const float* __restrict__ w1,
    const float* __restrict__ w2, const float* __restrict__ w3,
    const float* __restrict__ w4, const float* __restrict__ w5,
    u16* __restrict__ d0, u16* __restrict__ d1, u16* __restrict__ d2,
    u16* __restrict__ d3, u16* __restrict__ d4, u16* __restrict__ d5) {
    int blk = blockIdx.x;
    const float* s;
    u16* d;
    int base;
    float sc = 1.0f;
    if (blk < 512) {
        int seg = blk >> 7, lb = blk & 127;
        s = seg == 0 ? w0 : seg == 1 ? w1 : seg == 2 ? w2 : w3;
        d = seg == 0 ? d0 : seg == 1 ? d1 : seg == 2 ? d2 : d3;
        base = lb * 2048;
        if (seg == 0) sc = C1_FOLD;
    } else if (blk < 1024) {
        s = w4; d = d4; base = (blk - 512) * 2048;
    } else {
        s = w5; d = d5; base = (blk - 1024) * 2048;
    }
    int i = base + threadIdx.x * 8;
    float4 a = *reinterpret_cast<const float4*>(s + i);
    float4 b = *reinterpret_cast<const float4*>(s + i + 4);
    ushort4 oa, ob;
    oa.x = f2b(a.x * sc); oa.y = f2b(a.y * sc);
    oa.z = f2b(a.z * sc); oa.w = f2b(a.w * sc);
    ob.x = f2b(b.x * sc); ob.y = f2b(b.y * sc);
    ob.z = f2b(b.z * sc); ob.w = f2b(b.w * sc);
    *reinterpret_cast<ushort4*>(d + i) = oa;
    *reinterpret_cast<ushort4*>(d + i + 4) = ob;
}

// concat b_q*C1 | b_k | b_v -> bqkv[1536]
__global__ __launch_bounds__(256) void concat_bias(const float* __restrict__ bq,
                                                   const float* __restrict__ bk,
                                                   const float* __restrict__ bv,
                                                   float* __restrict__ dst) {
    int i = blockIdx.x * 256 + threadIdx.x;
    float v = i < 512 ? bq[i] * C1_FOLD : (i < 1024 ? bk[i - 512] : bv[i - 1024]);
    dst[i] = v;
}

// ---------------------------------------------------------------------------
// LayerNorm (unbiased var, ddof=1), fp32 in -> bf16 out. 1 wave / 512-row.
// ---------------------------------------------------------------------------
__global__ __launch_bounds__(256) void ln_rows(const float* __restrict__ x,
                                               u16* __restrict__ out) {
    int row = blockIdx.x * 4 + (threadIdx.x >> 6);
    int l = threadIdx.x & 63;
    const float* xr = x + (size_t)row * DMODEL + l * 8;
    float4 a = *reinterpret_cast<const float4*>(xr);
    float4 b = *reinterpret_cast<const float4*>(xr + 4);
    float s = a.x + a.y + a.z + a.w + b.x + b.y + b.z + b.w;
    float q = a.x * a.x + a.y * a.y + a.z * a.z + a.w * a.w +
              b.x * b.x + b.y * b.y + b.z * b.z + b.w * b.w;
#pragma unroll
    for (int d = 32; d >= 1; d >>= 1) {
        s += __shfl_xor(s, d, 64);
        q += __shfl_xor(q, d, 64);
    }
    float mean = s * (1.f / 512.f);
    float var = (q - 512.f * mean * mean) * (1.f / 511.f);
    float rs = rsqrtf(var + 1e-6f);
    ushort4 o0, o1;
    o0.x = f2b((a.x - mean) * rs); o0.y = f2b((a.y - mean) * rs);
    o0.z = f2b((a.z - mean) * rs); o0.w = f2b((a.w - mean) * rs);
    o1.x = f2b((b.x - mean) * rs); o1.y = f2b((b.y - mean) * rs);
    o1.z = f2b((b.z - mean) * rs); o1.w = f2b((b.w - mean) * rs);
    u16* op = out + (size_t)row * DMODEL + l * 8;
    *reinterpret_cast<ushort4*>(op) = o0;
    *reinterpret_cast<ushort4*>(op + 4) = o1;
}

// ---------------------------------------------------------------------------
// GEMM: C[M,N] = A[M,K] @ W[N,K]^T, 2-phase double-buffered (proven).
// 1D grid + chunked XCD swizzle (round-12 win): each XCD owns contiguous
// M-panels -> A-panel fetched once per XCD, then L2-hits.
// NX = N-tiles (compile-time). OUTMODE: 0 = bf16 row-major, 1 = fp32
// row-major, 3 = fused QKV (qk [M][1024] / V8 (B,S/32,4,512,8)).
// ---------------------------------------------------------------------------
template <bool RELU, bool RESID, int OUTMODE, int NX>
__global__ __launch_bounds__(256, 2) void gemm_nt(
    const u16* __restrict__ A, const u16* __restrict__ W,
    const float* __restrict__ bias, const float* __restrict__ resid,
    void* __restrict__ Cout, void* __restrict__ Cout2, int N, int K) {
    __shared__ u16 Als[2][128 * 64];
    __shared__ u16 Bls[2][128 * 64];
    const int tid = threadIdx.x;
    const int l = tid & 63, w = tid >> 6;
    const int nwg = gridDim.x;
    const int lb = (blockIdx.x & 7) * (nwg >> 3) + (blockIdx.x >> 3);
    const int m0 = (lb / NX) * 128;
    const int n0 = (lb % NX) * 128;
    const int wr = (w >> 1) * 64, wc = (w & 1) * 64;
    const int lhi = l >> 4, l15 = l & 15, l7 = l & 7;

    f32x4 acc[4][4] = {};

    const int srow = l >> 3;
    const int scol = ((l & 7) * 8) ^ (srow << 3);

    auto stage = [&](int buf, int kt) {
#pragma unroll
        for (int i = 0; i < 4; ++i) {
            int cc = w * 4 + i;
            int grow = cc * 8 + srow;
            gload_lds16(&A[(size_t)(m0 + grow) * K + kt + scol],
                        &Als[buf][cc * 512]);
            gload_lds16(&W[(size_t)(n0 + grow) * K + kt + scol],
                        &Bls[buf][cc * 512]);
        }
    };

    auto compute = [&](int buf) {
#pragma unroll
        for (int kk = 0; kk < 2; ++kk) {
            const int koff = (kk * 32 + lhi * 8) ^ (l7 << 3);
            bf16x8 af[4], bfr[4];
#pragma unroll
            for (int m = 0; m < 4; ++m)
                af[m] = *reinterpret_cast<const bf16x8*>(
                    &Als[buf][(wr + m * 16 + l15) * 64 + koff]);
#pragma unroll
            for (int n = 0; n < 4; ++n)
                bfr[n] = *reinterpret_cast<const bf16x8*>(
                    &Bls[buf][(wc + n * 16 + l15) * 64 + koff]);
#pragma unroll
            for (int m = 0; m < 4; ++m)
#pragma unroll
                for (int n = 0; n < 4; ++n)
                    acc[m][n] = __builtin_amdgcn_mfma_f32_16x16x32_bf16(
                        af[m], bfr[n], acc[m][n], 0, 0, 0);
        }
    };

    stage(0, 0);
    asm volatile("s_waitcnt vmcnt(0)" ::: "memory");
    __builtin_amdgcn_s_barrier();

    for (int kt = 0; kt < K; kt += 128) {
        if (kt + 64 < K) stage(1, kt + 64);
        __builtin_amdgcn_sched_barrier(0);
        compute(0);
        asm volatile("s_waitcnt vmcnt(0)" ::: "memory");
        __builtin_amdgcn_s_barrier();
        if (kt + 128 < K) stage(0, kt + 128);
        __builtin_amdgcn_sched_barrier(0);
        compute(1);
        asm volatile("s_waitcnt vmcnt(0)" ::: "memory");
        __builtin_amdgcn_s_barrier();
    }

    int colg[4];
    float bv[4];
#pragma unroll
    for (int cn = 0; cn < 4; ++cn) {
        colg[cn] = n0 + wc + cn * 16 + l15;
        bv[cn] = bias[colg[cn]];
    }
#pragma unroll
    for (int am = 0; am < 4; ++am) {
        int rowg = m0 + wr + am * 16 + 4 * lhi;
#pragma unroll
        for (int cn = 0; cn < 4; ++cn) {
            float v[4];
#pragma unroll
            for (int r = 0; r < 4; ++r) {
                float t = acc[am][cn][r] + bv[cn];
                if constexpr (RELU) t = fmaxf(t, 0.f);
                if constexpr (RESID)
                    t += resid[(size_t)(rowg + r) * N + colg[cn]];
                v[r] = t;
            }
            if constexpr (OUTMODE == 0) {
                u16* o = (u16*)Cout;
#pragma unroll
                for (int r = 0; r < 4; ++r)
                    o[(size_t)(rowg + r) * N + colg[cn]] = f2b(v[r]);
            } else if constexpr (OUTMODE == 1) {
                float* o = (float*)Cout;
#pragma unroll
                for (int r = 0; r < 4; ++r)
                    o[(size_t)(rowg + r) * N + colg[cn]] = v[r];
            } else {
                // fused QKV: n0 is block-uniform
                if (n0 < 1024) {
                    u16* o = (u16*)Cout;  // qk buffer [M][1024]
#pragma unroll
                    for (int r = 0; r < 4; ++r)
                        o[(size_t)(rowg + r) * 1024 + colg[cn]] = f2b(v[r]);
                } else {
                    // V8 (B, S/32, 4, 512, 8): 4 consecutive keys share
                    // (kk, hb, s), j = 0..3 -> one contiguous 8B store
                    u16* o = (u16*)Cout2;
                    int bb = rowg >> 11, sloc = rowg & 2047;  // sloc % 4 == 0
                    int dg = colg[cn] - 1024;
                    int kk = sloc >> 5, hb = (sloc >> 4) & 1, ss = (sloc >> 2) & 3;
                    ushort4 pk;
                    pk.x = f2b(v[0]); pk.y = f2b(v[1]);
                    pk.z = f2b(v[2]); pk.w = f2b(v[3]);
                    *reinterpret_cast<ushort4*>(
                        &o[(size_t)(bb * 64 + kk) * 16384 + ss * 4096 + dg * 8 +
                           hb * 4]) = pk;
                }
            }
        }
    }
}

// ---------------------------------------------------------------------------
// Flash attention v13: register-blocked q=64/wave (4 q-groups). K-fragment
// LDS reads are q-group-independent -> total LDS-pipe traffic HALVES vs
// q=32/wave (the dominant pipe per round-12 accounting). 2 waves/SIMD;
// ILP from 4 independent q-group chains substitutes for TLP.
// K LDS (source-swizzled) + V8 LDS (one b128 B-frag), swapped QK^T
// (C1 pre-folded), clamped no-max softmax, PV 16x16x32, row-sum via
// MFMA(ones). Block = 256 q x (b,h), 4 waves; grid 512 (XCD-swizzled).
// ---------------------------------------------------------------------------
__global__ __launch_bounds__(256, 2) void attn_fwd(
    const u16* __restrict__ qk, const u16* __restrict__ v8,
    const int* __restrict__ mask, u16* __restrict__ out) {
    __shared__ u16 Kls[2][64 * 64];
    __shared__ u16 Vls[2][8 * 512];
    const int tid = threadIdx.x;
    const int l = tid & 63, w = tid >> 6;
    const int lhi = l >> 4, l15 = l & 15;
    const int lb = (blockIdx.x & 7) * 64 + (blockIdx.x >> 3);  // XCD swizzle
    const int qt = lb & 7, bh = lb >> 3;
    const int b = bh >> 3, h = bh & 7;
    const int q0 = qt * 256 + w * 64;

    const u16* Qb = qk + (size_t)b * SEQ * 1024 + h * 64;
    const u16* Kb = Qb + 512;
    const u16* Vb8 = v8 + (size_t)b * 1048576 + h * 512;
    const int* Mb = mask + b * SEQ;

    const int srow = l >> 3;
    const int scol = ((l & 7) ^ srow) << 3;

    bf16x8 qf[4][2];
#pragma unroll
    for (int g = 0; g < 4; ++g) {
        size_t qa = (size_t)(q0 + g * 16 + l15) * 1024 + lhi * 8;
        qf[g][0] = *reinterpret_cast<const bf16x8*>(&Qb[qa]);
        qf[g][1] = *reinterpret_cast<const bf16x8*>(&Qb[qa + 32]);
    }

    bf16x8 ones8;
#pragma unroll
    for (int i = 0; i < 8; ++i) ones8[i] = (__bf16)1.0f;

    int allone;
    {
        int acc = 1;
#pragma unroll
        for (int i = 0; i < 8; ++i) {
            int4 mm = *reinterpret_cast<const int4*>(&Mb[l * 32 + i * 4]);
            acc &= mm.x & mm.y & mm.z & mm.w;
        }
        allone = __all(acc == 1);
    }

    f32x4 oacc[4][4] = {};
    f32x4 osum[4] = {};

    auto stage = [&](int buf, int kv) {
#pragma unroll
        for (int i = 0; i < 2; ++i) {
            int cc = w * 2 + i;
            int row = cc * 8 + srow;
            gload_lds16(&Kb[(size_t)(kv + row) * 1024 + scol], &Kls[buf][cc * 512]);
            gload_lds16(&Vb8[(size_t)((kv >> 5) + (cc >> 2)) * 16384 +
                             (cc & 3) * 4096 + l * 8],
                        &Vls[buf][cc * 512]);
        }
    };

    const int sw = (l15 & 7) << 3;

    auto tile = [&](int buf, int kv, bool pf, int pbuf, int pkv) {
        if (pf) stage(pbuf, pkv);
        __builtin_amdgcn_sched_barrier(0);

        // --- QK^T (swapped): sc[g][ks][r] = S[key=kv+ks*16+4lhi+r][q=l15+16g]
        // K fragments read ONCE per ks, consumed by all 4 q-groups.
        f32x4 sc[4][4];
        __builtin_amdgcn_s_setprio(1);
#pragma unroll
        for (int ks = 0; ks < 4; ++ks) {
            int krow = ks * 16 + l15;
            bf16x8 ka0 = *reinterpret_cast<const bf16x8*>(
                &Kls[buf][krow * 64 + ((lhi * 8) ^ sw)]);
            bf16x8 ka1 = *reinterpret_cast<const bf16x8*>(
                &Kls[buf][krow * 64 + ((32 + lhi * 8) ^ sw)]);
#pragma unroll
            for (int g = 0; g < 4; ++g) {
                f32x4 z = {};
                z = __builtin_amdgcn_mfma_f32_16x16x32_bf16(ka0, qf[g][0], z, 0, 0, 0);
                z = __builtin_amdgcn_mfma_f32_16x16x32_bf16(ka1, qf[g][1], z, 0, 0, 0);
                sc[g][ks] = z;
            }
        }
        __builtin_amdgcn_s_setprio(0);

        if (!allone) {
            int4 mm[4];
#pragma unroll
            for (int ks = 0; ks < 4; ++ks)
                mm[ks] = *reinterpret_cast<const int4*>(&Mb[kv + ks * 16 + 4 * lhi]);
#pragma unroll
            for (int ks = 0; ks < 4; ++ks) {
#pragma unroll
                for (int g = 0; g < 4; ++g) {
                    if (mm[ks].x == 0) sc[g][ks][0] = -3e38f;
                    if (mm[ks].y == 0) sc[g][ks][1] = -3e38f;
                    if (mm[ks].z == 0) sc[g][ks][2] = -3e38f;
                    if (mm[ks].w == 0) sc[g][ks][3] = -3e38f;
                }
            }
        }

        // --- clamped no-max softmax: p = exp2(min(s, 30)) (C1 pre-folded).
        u32x4 pku[4][2];
#pragma unroll
        for (int g = 0; g < 4; ++g) {
#pragma unroll
            for (int ks = 0; ks < 4; ++ks) {
                float p0 = ex2(fminf(sc[g][ks][0], 30.f));
                float p1 = ex2(fminf(sc[g][ks][1], 30.f));
                float p2 = ex2(fminf(sc[g][ks][2], 30.f));
                float p3 = ex2(fminf(sc[g][ks][3], 30.f));
                pku[g][ks >> 1][(ks & 1) * 2 + 0] = pack2(p0, p1);
                pku[g][ks >> 1][(ks & 1) * 2 + 1] = pack2(p2, p3);
            }
        }

        // --- PV at 16x16x32: V B-frag read ONCE per (kp,dc), consumed by
        // all 4 q-groups; row-sum MFMA with ones for the denominator.
        __builtin_amdgcn_s_setprio(1);
#pragma unroll
        for (int kp = 0; kp < 2; ++kp) {
#pragma unroll
            for (int dc = 0; dc < 4; ++dc) {
                bf16x8 vb8 = *reinterpret_cast<const bf16x8*>(
                    &Vls[buf][(kp * 4 + lhi) * 512 + (dc * 16 + l15) * 8]);
#pragma unroll
                for (int g = 0; g < 4; ++g)
                    oacc[g][dc] = __builtin_amdgcn_mfma_f32_16x16x32_bf16(
                        __builtin_bit_cast(bf16x8, pku[g][kp]), vb8, oacc[g][dc],
                        0, 0, 0);
            }
#pragma unroll
            for (int g = 0; g < 4; ++g)
                osum[g] = __builtin_amdgcn_mfma_f32_16x16x32_bf16(
                    __builtin_bit_cast(bf16x8, pku[g][kp]), ones8, osum[g],
                    0, 0, 0);
        }
        __builtin_amdgcn_s_setprio(0);

        asm volatile("s_waitcnt vmcnt(0)" ::: "memory");
        __builtin_amdgcn_s_barrier();
    };

    stage(0, 0);
    asm volatile("s_waitcnt vmcnt(0)" ::: "memory");
    __builtin_amdgcn_s_barrier();

    for (int tt = 0; tt < 16; ++tt) {
        const int base = tt * 128;
        tile(0, base, true, 1, base + 64);
        tile(1, base + 64, tt < 15, 0, base + 128);
    }

    // --- epilogue: oacc row = q = 4lhi+r, col d = 16dc+l15; osum[g][r] is
    // the matching row's denominator.
#pragma unroll
    for (int g = 0; g < 4; ++g) {
#pragma unroll
        for (int r = 0; r < 4; ++r) {
            float inv = 1.f / osum[g][r];
            size_t rowa =
                ((size_t)b * SEQ + q0 + g * 16 + 4 * lhi + r) * DMODEL + h * 64;
#pragma unroll
            for (int dc = 0; dc < 4; ++dc)
                out[rowa + dc * 16 + l15] = f2b(oacc[g][dc][r] * inv);
        }
    }
}

// ---------------------------------------------------------------------------
extern "C" void kernel_launch(void* const* d_in, const int* in_sizes, int n_in,
                              void* d_out, int out_size, void* d_ws,
                              size_t ws_size, hipStream_t stream) {
    const float* x = (const float*)d_in[0];
    const int* mask = (const int*)d_in[1];
    const float* w_q = (const float*)d_in[2];
    const float* b_q = (const float*)d_in[3];
    const float* w_k = (const float*)d_in[4];
    const float* b_k = (const float*)d_in[5];
    const float* w_v = (const float*)d_in[6];
    const float* b_v = (const float*)d_in[7];
    const float* w_o = (const float*)d_in[8];
    const float* b_o = (const float*)d_in[9];
    const float* w_1 = (const float*)d_in[10];
    const float* b_1 = (const float*)d_in[11];
    const float* w_2 = (const float*)d_in[12];
    const float* b_2 = (const float*)d_in[13];

    char* ws = (char*)d_ws;
    const size_t MB = 1024ull * 1024ull;
    u16* lnx = (u16*)(ws + 0);          // 16 MiB; reused as attn_out
    u16* qkb = (u16*)(ws + 16 * MB);    // 32 MiB [16,48): q|k interleaved rows
    u16* v8 = (u16*)(ws + 48 * MB);     // 16 MiB [48,64): (B,S/32,4,512,8)
    u16* lnx1 = (u16*)(ws + 16 * MB);   // after attn, qkb dead
    u16* hbuf = (u16*)(ws + 32 * MB);   // 64 MiB [32,96); qkb-hi, v8 dead
    u16* wqkv = (u16*)(ws + 96 * MB);   // [1536][512] (q|k|v rows contiguous)
    u16* wob = wqkv + 3 * 262144;
    u16* w1b = wqkv + 4 * 262144;
    u16* w2b = w1b + 1048576;
    float* bqkv = (float*)(w2b + 1048576);  // 1536 floats
    u16* attn_o = lnx;
    float* x1 = (float*)d_out;

    cast_weights<<<1536, 256, 0, stream>>>(
        w_q, w_k, w_v, w_o, w_1, w_2, wqkv, wqkv + 262144, wqkv + 2 * 262144,
        wob, w1b, w2b);
    concat_bias<<<6, 256, 0, stream>>>(b_q, b_k, b_v, bqkv);
    ln_rows<<<4096, 256, 0, stream>>>(x, lnx);

    gemm_nt<false, false, 3, 12><<<1536, 256, 0, stream>>>(
        lnx, wqkv, bqkv, nullptr, qkb, v8, 1536, 512);
    attn_fwd<<<512, 256, 0, stream>>>(qkb, v8, mask, attn_o);
    gemm_nt<false, true, 1, 4><<<512, 256, 0, stream>>>(
        attn_o, wob, b_o, x, x1, nullptr, 512, 512);
    ln_rows<<<4096, 256, 0, stream>>>(x1, lnx1);
    gemm_nt<true, false, 0, 16><<<2048, 256, 0, stream>>>(
        lnx1, w1b, b_1, nullptr, hbuf, nullptr, 2048, 512);
    gemm_nt<false, true, 1, 4><<<512, 256, 0, stream>>>(
        hbuf, w2b, b_2, x1, (float*)d_out, nullptr, 512, 2048);
}